// Round 12
// baseline (72.379 us; speedup 1.0000x reference)
//
#include <hip/hip_runtime.h>
#include <math.h>

#pragma clang fp contract(off)

#define LL 4096
#define FF 128
#define NB 32
#define BASE 16
#define NBLK 256
#define NOB 16

__device__ __forceinline__ float sani(float v) {
    return (fabsf(v) <= 3.0e38f) ? v : 0.0f;
}

// ---------- K1: per-tile sequential totals (direct, coalesced) ----------
__global__ __launch_bounds__(256) void k_tiles(const float* __restrict__ x,
                                               float2* __restrict__ T0) {
    const int pair = (int)blockIdx.x;     // 0..127
    const int b    = (int)blockIdx.y;     // 0..31
    const int tid  = (int)threadIdx.x;
    const int f    = tid & 127;
    const int tile = pair * 2 + (tid >> 7);
    const float* xb = x + ((size_t)b * LL + (size_t)tile * 16) * FF + f;
    float cs, cs2;
    {
        const float v = sani(xb[0]);
        cs = v; cs2 = __fmul_rn(v, v);
    }
#pragma unroll
    for (int u = 1; u < 16; ++u) {
        const float v = sani(xb[(size_t)u * FF]);
        cs  = __fadd_rn(cs,  v);
        cs2 = __fadd_rn(cs2, __fmul_rn(v, v));
    }
    T0[((size_t)b * NBLK + tile) * FF + f] = make_float2(cs, cs2);
}

// ---------- K2a: in-place s1 (RN scan within each 16-group of T0) ----------
__global__ __launch_bounds__(128) void k_pref_a(float2* __restrict__ T0) {
    const int g = (int)blockIdx.x & 15;
    const int b = (int)blockIdx.x >> 4;   // grid 512 = 32*16
    const int f = (int)threadIdx.x;
    float2* p = T0 + ((size_t)b * NBLK + (size_t)g * 16) * FF + f;
    float2 t[16];
#pragma unroll
    for (int i = 0; i < 16; ++i) t[i] = p[(size_t)i * FF];
    float sx = t[0].x, sy = t[0].y;       // s1[0] = T0[0], already in place
#pragma unroll
    for (int i = 1; i < 16; ++i) {
        sx = __fadd_rn(sx, t[i].x);
        sy = __fadd_rn(sy, t[i].y);
        p[(size_t)i * FF] = make_float2(sx, sy);
    }
}

// ---------- K2b: S2 = RN scan of group totals ----------
__global__ __launch_bounds__(128) void k_pref_b(const float2* __restrict__ S1,
                                                float2* __restrict__ S2) {
    const int b = (int)blockIdx.x;        // 32
    const int f = (int)threadIdx.x;
    const float2* base = S1 + (size_t)b * NBLK * FF + f;
    float2* s2 = S2 + (size_t)b * NOB * FF + f;
    float2 t = base[(size_t)15 * FF];
    float sx = t.x, sy = t.y;
    s2[0] = t;
    for (int g = 1; g < NOB; ++g) {
        const float2 tg = base[(size_t)(g * 16 + 15) * FF];
        sx = __fadd_rn(sx, tg.x);
        sy = __fadd_rn(sy, tg.y);
        s2[(size_t)g * FF] = make_float2(sx, sy);
    }
}

// compose P (exact r6 op order): P[B] = s1[B] (+ RN S2[g-1]); B<0 -> 0
__device__ __forceinline__ float2 PB_load(const float2* __restrict__ S1,
                                          const float2* __restrict__ S2,
                                          int b, int B, int f) {
    if (B < 0) return make_float2(0.0f, 0.0f);
    float2 p = S1[((size_t)b * NBLK + B) * FF + f];
    const int g = B >> 4;
    if (g > 0) {
        const float2 s2 = S2[((size_t)b * NOB + (g - 1)) * FF + f];
        p.x = __fadd_rn(p.x, s2.x);
        p.y = __fadd_rn(p.y, s2.y);
    }
    return p;
}

// ---------- K3: cooperative halo-shared register-chain window kernel ----------
// Block = (pair, b): tiles 2p, 2p+1 x 128 f. 256 threads: t = tid>>7 owns tile 2p+t.
// Position frame (per owning tile T): p = x_row - (T*16 - 16); window reads p in [5,40].
//   p 0..15  -> VP (prev tile chain)   p 16..31 -> VO (own)   p 32..40 -> VN (next rows 0..8)
// t=0 computes VP (tile 2p-1) + VO (tile 2p) itself; gets VN from t=1 via LDS.
// t=1 computes VO (tile 2p+1) + VN (tile 2p+2 rows 0..8); gets VP rows 5..15 from t=0 via LDS.
template<bool GUARD>
__device__ __forceinline__ void win4_body(const float* __restrict__ xcolB,
                                          float* __restrict__ out,
                                          const float2* __restrict__ S1,
                                          const float2* __restrict__ S2,
                                          int b, int f, int t, int pair,
                                          float* __restrict__ Ax, float* __restrict__ Ay,
                                          float* __restrict__ Bx, float* __restrict__ By,
                                          float ws0, float ws1, float ws2) {
    const int tileO = pair * 2 + t;

    float VPx[16], VPy[16], VOx[16], VOy[16], VNx[9], VNy[9], xr[16];

#define CHAINN(N, r0, PP, Cx, Cy, SAVEXR)                                \
    {                                                                    \
        float cs = 0.0f, cs2 = 0.0f;                                     \
        _Pragma("unroll")                                                \
        for (int u = 0; u < (N); ++u) {                                  \
            float v = 0.0f;                                              \
            if (!GUARD || ((unsigned)((r0) + u) < (unsigned)LL))         \
                v = sani(xcolB[(size_t)((r0) + u) * FF]);                \
            if (SAVEXR) xr[u] = v;                                       \
            if (u == 0) { cs = v; cs2 = __fmul_rn(v, v); }               \
            else { cs = __fadd_rn(cs, v);                                \
                   cs2 = __fadd_rn(cs2, __fmul_rn(v, v)); }              \
            Cx[u] = __fadd_rn(cs,  (PP).x);                              \
            Cy[u] = __fadd_rn(cs2, (PP).y);                              \
        }                                                                \
    }

    // ---- phase 1: chains + LDS halo writes ----
    if (t == 0) {
        const float2 PH = PB_load(S1, S2, b, tileO - 2, f);
        const float2 PO = PB_load(S1, S2, b, tileO - 1, f);
        CHAINN(16, (tileO - 1) * 16, PH, VPx, VPy, false)   // prev tile (full chain)
        CHAINN(16, tileO * 16,       PO, VOx, VOy, true)    // own tile
#pragma unroll
        for (int i = 5; i < 16; ++i) {                      // share own rows 5..15
            Ax[(i - 5) * FF + f] = VOx[i];
            Ay[(i - 5) * FF + f] = VOy[i];
        }
    } else {
        const float2 PO = PB_load(S1, S2, b, tileO - 1, f);
        float2 PN = make_float2(0.0f, 0.0f);
        if (!GUARD || (tileO + 1 <= NBLK - 1))
            PN = PB_load(S1, S2, b, tileO, f);
        CHAINN(16, tileO * 16,       PO, VOx, VOy, true)    // own tile
        CHAINN(9,  (tileO + 1) * 16, PN, VNx, VNy, false)   // next tile rows 0..8
#pragma unroll
        for (int i = 0; i < 9; ++i) {                       // share own rows 0..8
            Bx[i * FF + f] = VOx[i];
            By[i * FF + f] = VOy[i];
        }
    }
    __syncthreads();
    // ---- phase 2: LDS halo reads ----
    if (t == 0) {
#pragma unroll
        for (int i = 0; i < 9; ++i) { VNx[i] = Bx[i * FF + f]; VNy[i] = By[i * FF + f]; }
    } else {
#pragma unroll
        for (int i = 5; i < 16; ++i) { VPx[i] = Ax[(i - 5) * FF + f]; VPy[i] = Ay[(i - 5) * FF + f]; }
    }
#undef CHAINN

    // ---- window phase (identical to r9-verified) ----
    auto GX = [&](int p) -> float {
        return p < 16 ? VPx[p] : (p < 32 ? VOx[p - 16] : VNx[p - 32]);
    };
    auto GY = [&](int p) -> float {
        return p < 16 ? VPy[p] : (p < 32 ? VOy[p - 16] : VNy[p - 32]);
    };

    const int lbase = tileO * 16;
    float* ob = out + (size_t)lbase * FF;

#pragma unroll
    for (int u = 0; u < 16; ++u) {
        const int l = lbase + u;
        const float xc = xr[u];
        const float g5  = (l >= 2  && l <= LL - 3)  ? ws0 : 0.0f;
        const float g10 = (l >= 5  && l <= LL - 5)  ? ws1 : 0.0f;
        const float g20 = (l >= 10 && l <= LL - 10) ? ws2 : 0.0f;
        float o;
        {   // w=5:  positions u+18 / u+13
            const float mean = (GX(u + 18) - GX(u + 13)) * 0.2f;
            const float m2   = (GY(u + 18) - GY(u + 13)) * 0.2f;
            const float var  = fmaxf(m2 - mean * mean, 0.0f);
            o = g5 * ((xc - mean) * rsqrtf(var + 1e-5f));
        }
        {   // w=10: positions u+20 / u+10
            const float mean = (GX(u + 20) - GX(u + 10)) * 0.1f;
            const float m2   = (GY(u + 20) - GY(u + 10)) * 0.1f;
            const float var  = fmaxf(m2 - mean * mean, 0.0f);
            o += g10 * ((xc - mean) * rsqrtf(var + 1e-5f));
        }
        {   // w=20: positions u+25 / u+5
            const float mean = (GX(u + 25) - GX(u + 5)) * 0.05f;
            const float m2   = (GY(u + 25) - GY(u + 5)) * 0.05f;
            const float var  = fmaxf(m2 - mean * mean, 0.0f);
            o += g20 * ((xc - mean) * rsqrtf(var + 1e-5f));
        }
        ob[(size_t)u * FF] = o;
    }
}

__global__ __launch_bounds__(256) void k_win4(const float* __restrict__ x,
                                              const float* __restrict__ w,
                                              const float2* __restrict__ S1,
                                              const float2* __restrict__ S2,
                                              float* __restrict__ out) {
    __shared__ float Ax[11 * FF], Ay[11 * FF];   // t=0 tile rows 5..15
    __shared__ float Bx[9 * FF],  By[9 * FF];    // t=1 tile rows 0..8
    const int pair = (int)blockIdx.x;            // 0..127
    const int b    = (int)blockIdx.y;            // 0..31
    const int tid  = (int)threadIdx.x;
    const int t    = tid >> 7;                   // wave-uniform
    const int f    = tid & 127;

    // softmax over 3 weights (uniform)
    const float w0 = w[0], w1 = w[1], w2 = w[2];
    const float mx = fmaxf(w0, fmaxf(w1, w2));
    const float e0 = expf(w0 - mx), e1 = expf(w1 - mx), e2 = expf(w2 - mx);
    const float s  = e0 + e1 + e2;
    const float ws0 = e0 / s, ws1 = e1 / s, ws2 = e2 / s;

    const float* xcolB = x   + (size_t)b * LL * FF + f;
    float*       ocol  = out + (size_t)b * LL * FF + f;

    if (pair >= 1 && pair <= 126)
        win4_body<false>(xcolB, ocol, S1, S2, b, f, t, pair, Ax, Ay, Bx, By, ws0, ws1, ws2);
    else
        win4_body<true >(xcolB, ocol, S1, S2, b, f, t, pair, Ax, Ay, Bx, By, ws0, ws1, ws2);
}

// ---------- fallback: verified single-kernel r6 (if ws too small) ----------
__global__ __launch_bounds__(256) void fan_blocked(const float* __restrict__ x,
                                                   const float* __restrict__ w,
                                                   float* __restrict__ out) {
    __shared__ float2 V[LL];
    __shared__ float2 T0s[NBLK];
    __shared__ float2 T1[NOB];
    __shared__ float2 S2[NOB];
    const int col = blockIdx.x;
    const int f   = col & (FF - 1);
    const int b   = col >> 7;
    const int tid = (int)threadIdx.x;
    const float* xcol = x   + (size_t)b * LL * FF + f;
    float*       ocol = out + (size_t)b * LL * FF + f;
    for (int l = tid; l < LL; l += 256) {
        const float v = sani(xcol[(size_t)l * FF]);
        V[l] = make_float2(v, __fmul_rn(v, v));
    }
    __syncthreads();
    {
        const int bse = tid * BASE;
        float cs = V[bse].x, cs2 = V[bse].y;
        for (int u = 1; u < BASE; ++u) {
            const float2 e = V[bse + u];
            cs = __fadd_rn(cs, e.x); cs2 = __fadd_rn(cs2, e.y);
            V[bse + u] = make_float2(cs, cs2);
        }
        T0s[tid] = make_float2(cs, cs2);
    }
    __syncthreads();
    if (tid < NOB) {
        const int bse = tid * BASE;
        float cs = T0s[bse].x, cs2 = T0s[bse].y;
        for (int u = 1; u < BASE; ++u) {
            const float2 e = T0s[bse + u];
            cs = __fadd_rn(cs, e.x); cs2 = __fadd_rn(cs2, e.y);
            T0s[bse + u] = make_float2(cs, cs2);
        }
        T1[tid] = make_float2(cs, cs2);
    }
    __syncthreads();
    if (tid == 0) {
        float cs = T1[0].x, cs2 = T1[0].y;
        S2[0] = T1[0];
        for (int o = 1; o < NOB; ++o) {
            cs = __fadd_rn(cs, T1[o].x); cs2 = __fadd_rn(cs2, T1[o].y);
            S2[o] = make_float2(cs, cs2);
        }
    }
    __syncthreads();
    {
        const int blk = tid;
        if (blk > 0) {
            const int B = blk - 1, ob2 = B >> 4;
            float2 Pp = T0s[B];
            if (ob2 > 0) {
                const float2 s2 = S2[ob2 - 1];
                Pp = make_float2(__fadd_rn(Pp.x, s2.x), __fadd_rn(Pp.y, s2.y));
            }
            const int bse = blk * BASE;
            for (int u = 0; u < BASE; ++u) {
                const float2 sv = V[bse + u];
                V[bse + u] = make_float2(__fadd_rn(sv.x, Pp.x), __fadd_rn(sv.y, Pp.y));
            }
        }
    }
    __syncthreads();
    const float w0 = w[0], w1 = w[1], w2 = w[2];
    const float mx = fmaxf(w0, fmaxf(w1, w2));
    const float e0 = expf(w0 - mx), e1 = expf(w1 - mx), e2 = expf(w2 - mx);
    const float s  = e0 + e1 + e2;
    const float ws0 = e0 / s, ws1 = e1 / s, ws2 = e2 / s;
    auto PV = [&](int j) -> float2 {
        if (j <= 0) return make_float2(0.0f, 0.0f);
        int idx = j - 1; if (idx > LL - 1) idx = LL - 1;
        return V[idx];
    };
    for (int l = tid; l < LL; l += 256) {
        const float xc = sani(xcol[(size_t)l * FF]);
        const float2 A5 = PV(l + 3), B5 = PV(l - 2);
        const float2 A10 = PV(l + 5), B10 = PV(l - 5);
        const float2 A20 = PV(l + 10), B20 = PV(l - 10);
        const float g5  = (l >= 2  && l <= LL - 3)  ? ws0 : 0.0f;
        const float g10 = (l >= 5  && l <= LL - 5)  ? ws1 : 0.0f;
        const float g20 = (l >= 10 && l <= LL - 10) ? ws2 : 0.0f;
        float o;
        {
            const float mean = (A5.x - B5.x) * 0.2f;
            const float m2   = (A5.y - B5.y) * 0.2f;
            const float var  = fmaxf(m2 - mean * mean, 0.0f);
            o = g5 * ((xc - mean) * rsqrtf(var + 1e-5f));
        }
        {
            const float mean = (A10.x - B10.x) * 0.1f;
            const float m2   = (A10.y - B10.y) * 0.1f;
            const float var  = fmaxf(m2 - mean * mean, 0.0f);
            o += g10 * ((xc - mean) * rsqrtf(var + 1e-5f));
        }
        {
            const float mean = (A20.x - B20.x) * 0.05f;
            const float m2   = (A20.y - B20.y) * 0.05f;
            const float var  = fmaxf(m2 - mean * mean, 0.0f);
            o += g20 * ((xc - mean) * rsqrtf(var + 1e-5f));
        }
        ocol[(size_t)l * FF] = o;
    }
}

extern "C" void kernel_launch(void* const* d_in, const int* in_sizes, int n_in,
                              void* d_out, int out_size, void* d_ws, size_t ws_size,
                              hipStream_t stream) {
    const float* x = (const float*)d_in[0];
    const float* w = (const float*)d_in[1];
    float* out     = (float*)d_out;

    const size_t t0_bytes = (size_t)NB * NBLK * FF * sizeof(float2);   // 8 MiB
    if (ws_size >= 2 * t0_bytes) {                                     // 16 MiB
        float2* T0 = (float2*)d_ws;                                    // becomes s1 in place
        float2* S2 = (float2*)((char*)d_ws + t0_bytes);                // 0.5 MiB
        k_tiles <<<dim3(128, NB), dim3(256), 0, stream>>>(x, T0);
        k_pref_a<<<dim3(NB * 16), dim3(128), 0, stream>>>(T0);
        k_pref_b<<<dim3(NB),      dim3(128), 0, stream>>>(T0, S2);
        k_win4  <<<dim3(128, NB), dim3(256), 0, stream>>>(x, w, T0, S2, out);
    } else {
        fan_blocked<<<dim3(NB * FF), dim3(256), 0, stream>>>(x, w, out);
    }
}